// Round 6
// baseline (252.998 us; speedup 1.0000x reference)
//
#include <hip/hip_runtime.h>
#include <stdint.h>

#define B_ 8
#define S_ 1024
#define D_ 1024
#define H_ 16
#define DK_ 64
#define DV_ 64

typedef __attribute__((ext_vector_type(8))) short short8;
typedef __attribute__((ext_vector_type(4))) float f32x4;

__device__ __forceinline__ unsigned short f2bf(float f) {
  union { float f; unsigned u; } v; v.f = f;
  return (unsigned short)((v.u + 0x7fffu + ((v.u >> 16) & 1u)) >> 16);
}
__device__ __forceinline__ unsigned short f2bf_trunc(float f) {
  union { float f; unsigned u; } v; v.f = f;
  return (unsigned short)(v.u >> 16);
}

// async global->LDS, 16B per lane; LDS dest = wave-uniform base + lane*16
__device__ __forceinline__ void ld_lds16(const unsigned short* g, unsigned short* l) {
  __builtin_amdgcn_global_load_lds((const __attribute__((address_space(1))) void*)g,
                                   (__attribute__((address_space(3))) void*)l, 16, 0, 0);
}

// -------- fused prep: x fp32->bf16 (z>=4) + 4 weight transposes (z<4) --------
__global__ __launch_bounds__(256) void prep_kernel(const float* __restrict__ x,
                                                   unsigned short* __restrict__ xb,
                                                   const float* __restrict__ W0,
                                                   const float* __restrict__ W1,
                                                   const float* __restrict__ W2,
                                                   const float* __restrict__ W3,
                                                   unsigned short* __restrict__ T0,
                                                   unsigned short* __restrict__ T1,
                                                   unsigned short* __restrict__ T2,
                                                   unsigned short* __restrict__ T3) {
  const int z = blockIdx.z;
  if (z >= 4) {
    size_t blk = (size_t)(z - 4) * 256 + blockIdx.y * 16 + blockIdx.x;
    size_t i = (blk * 256 + threadIdx.x) * 4;
    float4 v = *(const float4*)(x + i);
    ushort4 o;
    o.x = f2bf(v.x); o.y = f2bf(v.y); o.z = f2bf(v.z); o.w = f2bf(v.w);
    *(ushort4*)(xb + i) = o;
    return;
  }
  __shared__ __align__(16) unsigned short tl[64][65];
  const float* W; unsigned short* Wt;
  switch (z) {
    case 0: W = W0; Wt = T0; break;
    case 1: W = W1; Wt = T1; break;
    case 2: W = W2; Wt = T2; break;
    default: W = W3; Wt = T3; break;
  }
  const int xx = threadIdx.x & 63;
  const int y4 = threadIdx.x >> 6;
  const int bn = blockIdx.x * 64;   // N base
  const int bk = blockIdx.y * 64;   // K base
  #pragma unroll
  for (int r = y4; r < 64; r += 4)
    tl[r][xx] = f2bf(W[(size_t)(bk + r) * 1024 + bn + xx]);
  __syncthreads();
  #pragma unroll
  for (int r = y4; r < 64; r += 4)
    Wt[(size_t)(bn + r) * 1024 + bk + xx] = tl[xx][r];
}

// ======================= shared GEMM pieces =======================
struct SJob { const unsigned short* g; unsigned short* l; };

// stage 128 rows x 64 cols (bf16) from G (row stride 1024) into L, linear dest,
// pre-swizzled source column blocks (cb ^ (r&7)).
__device__ __forceinline__ void stage128(const unsigned short* __restrict__ G,
                                         unsigned short* __restrict__ L, int t) {
  #pragma unroll
  for (int i = 0; i < 2; i++) {
    int s = i * 512 + t;
    int r = s >> 3, cb = s & 7;
    int c = cb ^ (r & 7);
    ld_lds16(G + (size_t)r * 1024 + c * 8, L + (size_t)s * 8);
  }
}

template <bool SW>
__device__ __forceinline__ f32x4 MM(short8 a, short8 b, f32x4 c) {
  if constexpr (SW) return __builtin_amdgcn_mfma_f32_16x16x32_bf16(b, a, c, 0, 0, 0);
  else              return __builtin_amdgcn_mfma_f32_16x16x32_bf16(a, b, c, 0, 0, 0);
}

// ============ m201-geometry K-tile: 256x256 block, per-wave 128x64 ============
// 4 phases x 16 MFMA (phase q: mi{2q,2q+1} x 4ni x 2kf); B-frags read once at
// q0 and HELD in regs (8x short8) -> 24 ds_read_b128 / 64 MFMA per tile.
// Staging: q0: A(T+1)h0, q1: A(T+1)h1 (A slot (T+1)%2 idle since end of T-1);
// q2: B(T+2)h0, q3: B(T+2)h1 (B slot T%2's reads drained at q0's lgkmcnt).
// vmcnt(4) at q3 certifies A(T+1)+B(T+1), leaves B(T+2) in flight.
template <bool SW, int VM>
__device__ __forceinline__ void ktile256(const unsigned short* __restrict__ As_,
                                         const unsigned short* __restrict__ Bs_,
                                         f32x4 (&acc)[8][4],
                                         SJob sA0, SJob sA1, SJob sB0, SJob sB1,
                                         int t, int wm, int wn, int l15, int quad, int l7) {
  const int cb0 = (quad ^ l7) * 8;
  const int cb1 = ((4 | quad) ^ l7) * 8;
  short8 bh0[4], bh1[4];
  short8 a0, a1, a2, a3;

  // ---------- phase 0: B-frags (held) + mi{0,1}; stage A(T+1) h0 ----------
  #pragma unroll
  for (int ni = 0; ni < 4; ni++) {
    bh0[ni] = *(const short8*)&Bs_[(wn + ni * 16 + l15) * 64 + cb0];
    bh1[ni] = *(const short8*)&Bs_[(wn + ni * 16 + l15) * 64 + cb1];
  }
  a0 = *(const short8*)&As_[(wm + 0 * 16 + l15) * 64 + cb0];
  a1 = *(const short8*)&As_[(wm + 0 * 16 + l15) * 64 + cb1];
  a2 = *(const short8*)&As_[(wm + 1 * 16 + l15) * 64 + cb0];
  a3 = *(const short8*)&As_[(wm + 1 * 16 + l15) * 64 + cb1];
  if (sA0.g) stage128(sA0.g, sA0.l, t);
  __builtin_amdgcn_s_barrier();
  asm volatile("s_waitcnt lgkmcnt(0)" ::: "memory");
  __builtin_amdgcn_s_setprio(1);
  #pragma unroll
  for (int ni = 0; ni < 4; ni++) {
    acc[0][ni] = MM<SW>(a0, bh0[ni], acc[0][ni]);
    acc[0][ni] = MM<SW>(a1, bh1[ni], acc[0][ni]);
    acc[1][ni] = MM<SW>(a2, bh0[ni], acc[1][ni]);
    acc[1][ni] = MM<SW>(a3, bh1[ni], acc[1][ni]);
  }
  __builtin_amdgcn_s_setprio(0);
  __builtin_amdgcn_s_barrier();

  // ---------- phase 1: mi{2,3}; stage A(T+1) h1 ----------
  a0 = *(const short8*)&As_[(wm + 2 * 16 + l15) * 64 + cb0];
  a1 = *(const short8*)&As_[(wm + 2 * 16 + l15) * 64 + cb1];
  a2 = *(const short8*)&As_[(wm + 3 * 16 + l15) * 64 + cb0];
  a3 = *(const short8*)&As_[(wm + 3 * 16 + l15) * 64 + cb1];
  if (sA1.g) stage128(sA1.g, sA1.l, t);
  __builtin_amdgcn_s_barrier();
  asm volatile("s_waitcnt lgkmcnt(0)" ::: "memory");
  __builtin_amdgcn_s_setprio(1);
  #pragma unroll
  for (int ni = 0; ni < 4; ni++) {
    acc[2][ni] = MM<SW>(a0, bh0[ni], acc[2][ni]);
    acc[2][ni] = MM<SW>(a1, bh1[ni], acc[2][ni]);
    acc[3][ni] = MM<SW>(a2, bh0[ni], acc[3][ni]);
    acc[3][ni] = MM<SW>(a3, bh1[ni], acc[3][ni]);
  }
  __builtin_amdgcn_s_setprio(0);
  __builtin_amdgcn_s_barrier();

  // ---------- phase 2: mi{4,5}; stage B(T+2) h0 ----------
  a0 = *(const short8*)&As_[(wm + 4 * 16 + l15) * 64 + cb0];
  a1 = *(const short8*)&As_[(wm + 4 * 16 + l15) * 64 + cb1];
  a2 = *(const short8*)&As_[(wm + 5 * 16 + l15) * 64 + cb0];
  a3 = *(const short8*)&As_[(wm + 5 * 16 + l15) * 64 + cb1];
  if (sB0.g) stage128(sB0.g, sB0.l, t);
  __builtin_amdgcn_s_barrier();
  asm volatile("s_waitcnt lgkmcnt(0)" ::: "memory");
  __builtin_amdgcn_s_setprio(1);
  #pragma unroll
  for (int ni = 0; ni < 4; ni++) {
    acc[4][ni] = MM<SW>(a0, bh0[ni], acc[4][ni]);
    acc[4][ni] = MM<SW>(a1, bh1[ni], acc[4][ni]);
    acc[5][ni] = MM<SW>(a2, bh0[ni], acc[5][ni]);
    acc[5][ni] = MM<SW>(a3, bh1[ni], acc[5][ni]);
  }
  __builtin_amdgcn_s_setprio(0);
  __builtin_amdgcn_s_barrier();

  // ---------- phase 3: mi{6,7}; stage B(T+2) h1; vmcnt ----------
  a0 = *(const short8*)&As_[(wm + 6 * 16 + l15) * 64 + cb0];
  a1 = *(const short8*)&As_[(wm + 6 * 16 + l15) * 64 + cb1];
  a2 = *(const short8*)&As_[(wm + 7 * 16 + l15) * 64 + cb0];
  a3 = *(const short8*)&As_[(wm + 7 * 16 + l15) * 64 + cb1];
  if (sB1.g) stage128(sB1.g, sB1.l, t);
  __builtin_amdgcn_s_barrier();
  asm volatile("s_waitcnt lgkmcnt(0)" ::: "memory");
  __builtin_amdgcn_s_setprio(1);
  #pragma unroll
  for (int ni = 0; ni < 4; ni++) {
    acc[6][ni] = MM<SW>(a0, bh0[ni], acc[6][ni]);
    acc[6][ni] = MM<SW>(a1, bh1[ni], acc[6][ni]);
    acc[7][ni] = MM<SW>(a2, bh0[ni], acc[7][ni]);
    acc[7][ni] = MM<SW>(a3, bh1[ni], acc[7][ni]);
  }
  __builtin_amdgcn_s_setprio(0);
  if constexpr (VM == 4) asm volatile("s_waitcnt vmcnt(4)" ::: "memory");
  if constexpr (VM == 0) asm volatile("s_waitcnt vmcnt(0)" ::: "memory");
  __builtin_amdgcn_s_barrier();
}

// full 256x256 gemm core: 16 K-tiles, A/B double-buffered
template <bool SW>
__device__ __forceinline__ void gemm_core256(const unsigned short* __restrict__ Ag,
                                             const unsigned short* __restrict__ Bg,
                                             unsigned short* __restrict__ Asl,
                                             unsigned short* __restrict__ Bsl,
                                             f32x4 (&acc)[8][4],
                                             int t, int wm, int wn, int l15, int quad, int l7) {
  unsigned short* A0 = Asl;
  unsigned short* A1 = Asl + 16384;
  unsigned short* B0s = Bsl;
  unsigned short* B1s = Bsl + 16384;

  // prologue: A(0), B(0), B(1); vmcnt(4) leaves B(1)'s 4 loads in flight
  stage128(Ag,              A0, t);
  stage128(Ag + 128 * 1024, A0 + 8192, t);
  stage128(Bg,              B0s, t);
  stage128(Bg + 128 * 1024, B0s + 8192, t);
  stage128(Bg + 64,              B1s, t);
  stage128(Bg + 64 + 128 * 1024, B1s + 8192, t);
  asm volatile("s_waitcnt vmcnt(4)" ::: "memory");
  __builtin_amdgcn_s_barrier();

  #pragma unroll 1
  for (int J = 0; J < 14; J += 2) {
    const unsigned short* Aj = Ag + (size_t)J * 64;
    const unsigned short* Bj = Bg + (size_t)J * 64;
    // tile J (slots 0): stage A(J+1)->slot1, B(J+2)->slot0
    ktile256<SW, 4>(A0, B0s, acc,
                    SJob{Aj + 64, A1}, SJob{Aj + 64 + 128 * 1024, A1 + 8192},
                    SJob{Bj + 128, B0s}, SJob{Bj + 128 + 128 * 1024, B0s + 8192},
                    t, wm, wn, l15, quad, l7);
    // tile J+1 (slots 1): stage A(J+2)->slot0, B(J+3)->slot1
    ktile256<SW, 4>(A1, B1s, acc,
                    SJob{Aj + 128, A0}, SJob{Aj + 128 + 128 * 1024, A0 + 8192},
                    SJob{Bj + 192, B1s}, SJob{Bj + 192 + 128 * 1024, B1s + 8192},
                    t, wm, wn, l15, quad, l7);
  }
  // tile 14 (slots 0): stage A(15)->slot1; full drain
  ktile256<SW, 0>(A0, B0s, acc,
                  SJob{Ag + 15 * 64, A1}, SJob{Ag + 15 * 64 + 128 * 1024, A1 + 8192},
                  SJob{nullptr, nullptr}, SJob{nullptr, nullptr},
                  t, wm, wn, l15, quad, l7);
  // tile 15 (slots 1): nothing in flight
  ktile256<SW, -1>(A1, B1s, acc,
                   SJob{nullptr, nullptr}, SJob{nullptr, nullptr},
                   SJob{nullptr, nullptr}, SJob{nullptr, nullptr},
                   t, wm, wn, l15, quad, l7);
}

// ------------- fused QKV GEMM: A (8192x1024), Bt (3072x1024), 256x256 tiles -------------
// grid (12,32): bxi 0..3 -> q (scaled), 4..7 -> k, 8..11 -> v (transposed, mask folded)
__global__ __launch_bounds__(512, 2) void gemm_qkv8(const unsigned short* __restrict__ A,
                                                    const unsigned short* __restrict__ Bt,
                                                    const float* __restrict__ bq,
                                                    const float* __restrict__ bk,
                                                    const float* __restrict__ bv,
                                                    const int* __restrict__ masks,
                                                    unsigned short* __restrict__ q,
                                                    unsigned short* __restrict__ kk,
                                                    unsigned short* __restrict__ vT) {
  extern __shared__ unsigned short lds[];
  unsigned short* Asl = lds;               // 2 x 256x64
  unsigned short* Bsl = lds + 2 * 16384;   // 2 x 256x64
  const int t = threadIdx.x;
  const int w = t >> 6, lane = t & 63;
  const int l15 = lane & 15, quad = lane >> 4, l7 = l15 & 7;
  const int bxi = blockIdx.x, byi = blockIdx.y;
  const int bm = byi * 256, bn = bxi * 256;
  const int wm = (w >> 2) * 128, wn = (w & 3) * 64;   // per-wave 128x64
  const bool vsec = (bxi >= 8);
  const unsigned short* Ag = A + (size_t)bm * 1024;
  const unsigned short* Bg = Bt + (size_t)bn * 1024;

  f32x4 acc[8][4] = {};
  if (!vsec) gemm_core256<false>(Ag, Bg, Asl, Bsl, acc, t, wm, wn, l15, quad, l7);
  else       gemm_core256<true >(Ag, Bg, Asl, Bsl, acc, t, wm, wn, l15, quad, l7);

  if (!vsec) {
    int sec = bxi >> 2;   // 0 -> q, 1 -> k
    const float* bsel = (sec == 0) ? bq : bk;
    unsigned short* dst = (sec == 0) ? q : kk;
    float scale = (sec == 0) ? 0.180336880f : 1.0f;  // 0.125*log2(e) folded into q
    #pragma unroll
    for (int ni = 0; ni < 4; ni++) {
      int c = (bxi & 3) * 256 + wn + ni * 16 + l15;
      float bvv = bsel[c];
      int hh = c >> 6, d = c & 63;
      #pragma unroll
      for (int mi = 0; mi < 8; mi++) {
        int row0 = bm + wm + mi * 16 + quad * 4;
        #pragma unroll
        for (int r = 0; r < 4; r++) {
          int row = row0 + r;
          int b = row >> 10, s = row & 1023;
          dst[(((size_t)(b * H_ + hh)) * S_ + s) * DK_ + d] = f2bf((acc[mi][ni][r] + bvv) * scale);
        }
      }
    }
  } else {
    // transposed accum: lane l15 -> row (s), quad*4+r -> col (d); mask folded
    #pragma unroll
    for (int ni = 0; ni < 4; ni++) {
      int cbase = (bxi & 3) * 256 + wn + ni * 16;
      #pragma unroll
      for (int mi = 0; mi < 8; mi++) {
        int row = bm + wm + mi * 16 + l15;
        int b = row >> 10, s = row & 1023;
        float mf = (masks[b * S_ + s] != 0) ? 1.0f : 0.0f;
        #pragma unroll
        for (int r = 0; r < 4; r++) {
          int c = cbase + quad * 4 + r;
          int hh = c >> 6, d = c & 63;
          vT[(((size_t)(b * H_ + hh)) * DV_ + d) * S_ + s] = f2bf((acc[mi][ni][r] + bv[c]) * mf);
        }
      }
    }
  }
}

// ===== old 256x128 core (ktile2, 3-slot) kept for gemm_out =====
template <bool SW, int VM>
__device__ __forceinline__ void ktile2(const unsigned short* __restrict__ As_,
                                       const unsigned short* __restrict__ Bs_,
                                       f32x4 (&acc)[4][4],
                                       SJob a0, SJob a1, SJob b2,
                                       int t, int wm, int wn, int l15, int quad, int l7) {
  const int cb0 = (quad ^ l7) * 8;
  const int cb1 = ((4 | quad) ^ l7) * 8;
  short8 af[4], bf[4];

  #pragma unroll
  for (int mi = 0; mi < 4; mi++)
    af[mi] = *(const short8*)&As_[(wm + mi * 16 + l15) * 64 + cb0];
  #pragma unroll
  for (int ni = 0; ni < 4; ni++)
    bf[ni] = *(const short8*)&Bs_[(wn + ni * 16 + l15) * 64 + cb0];
  if (a0.g) stage128(a0.g, a0.l, t);
  if (a1.g) stage128(a1.g, a1.l, t);
  __builtin_amdgcn_s_barrier();
  asm volatile("s_waitcnt lgkmcnt(0)" ::: "memory");
  __builtin_amdgcn_s_setprio(1);
  #pragma unroll
  for (int mi = 0; mi < 4; mi++)
    #pragma unroll
    for (int ni = 0; ni < 4; ni++)
      acc[mi][ni] = MM<SW>(af[mi], bf[ni], acc[mi][ni]);
  __builtin_amdgcn_s_setprio(0);
  __builtin_amdgcn_s_barrier();

  #pragma unroll
  for (int mi = 0; mi < 4; mi++)
    af[mi] = *(const short8*)&As_[(wm + mi * 16 + l15) * 64 + cb1];
  #pragma unroll
  for (int ni = 0; ni < 4; ni++)
    bf[ni] = *(const short8*)&Bs_[(wn + ni * 16 + l15) * 64 + cb1];
  if (b2.g) stage128(b2.g, b2.l, t);
  __builtin_amdgcn_s_barrier();
  asm volatile("s_waitcnt lgkmcnt(0)" ::: "memory");
  __builtin_amdgcn_s_setprio(1);
  #pragma unroll
  for (int mi = 0; mi < 4; mi++)
    #pragma unroll
    for (int ni = 0; ni < 4; ni++)
      acc[mi][ni] = MM<SW>(af[mi], bf[ni], acc[mi][ni]);
  __builtin_amdgcn_s_setprio(0);
  if constexpr (VM == 6) asm volatile("s_waitcnt vmcnt(6)" ::: "memory");
  if constexpr (VM == 0) asm volatile("s_waitcnt vmcnt(0)" ::: "memory");
  __builtin_amdgcn_s_barrier();
}

template <bool SW>
__device__ __forceinline__ void gemm_core(const unsigned short* __restrict__ Ag,
                                          const unsigned short* __restrict__ Bg,
                                          unsigned short* __restrict__ Asl,
                                          unsigned short* __restrict__ Bsl,
                                          f32x4 (&acc)[4][4],
                                          int t, int wm, int wn, int l15, int quad, int l7) {
  unsigned short* A0 = Asl;
  unsigned short* A1 = Asl + 16384;
  unsigned short* A2 = Asl + 32768;
  unsigned short* Bs0 = Bsl;
  unsigned short* Bs1 = Bsl + 8192;
  unsigned short* Bs2 = Bsl + 16384;

  stage128(Ag,                 A0, t);
  stage128(Ag + 128 * 1024,    A0 + 8192, t);
  stage128(Bg,                 Bs0, t);
  stage128(Ag + 64,                A1, t);
  stage128(Ag + 64 + 128 * 1024,   A1 + 8192, t);
  stage128(Bg + 64,                Bs1, t);
  asm volatile("s_waitcnt vmcnt(6)" ::: "memory");
  __builtin_amdgcn_s_barrier();

  #pragma unroll 1
  for (int J = 0; J < 12; J += 3) {
    const unsigned short* Aj = Ag + (size_t)J * 64;
    const unsigned short* Bj = Bg + (size_t)J * 64;
    ktile2<SW, 6>(A0, Bs0, acc,
                  SJob{Aj + 2 * 64, A2}, SJob{Aj + 2 * 64 + 128 * 1024, A2 + 8192},
                  SJob{Bj + 2 * 64, Bs2}, t, wm, wn, l15, quad, l7);
    ktile2<SW, 6>(A1, Bs1, acc,
                  SJob{Aj + 3 * 64, A0}, SJob{Aj + 3 * 64 + 128 * 1024, A0 + 8192},
                  SJob{Bj + 3 * 64, Bs0}, t, wm, wn, l15, quad, l7);
    ktile2<SW, 6>(A2, Bs2, acc,
                  SJob{Aj + 4 * 64, A1}, SJob{Aj + 4 * 64 + 128 * 1024, A1 + 8192},
                  SJob{Bj + 4 * 64, Bs1}, t, wm, wn, l15, quad, l7);
  }
  ktile2<SW, 6>(A0, Bs0, acc,
                SJob{Ag + 14 * 64, A2}, SJob{Ag + 14 * 64 + 128 * 1024, A2 + 8192},
                SJob{Bg + 14 * 64, Bs2}, t, wm, wn, l15, quad, l7);
  ktile2<SW, 6>(A1, Bs1, acc,
                SJob{Ag + 15 * 64, A0}, SJob{Ag + 15 * 64 + 128 * 1024, A0 + 8192},
                SJob{Bg + 15 * 64, Bs0}, t, wm, wn, l15, quad, l7);
  ktile2<SW, 0>(A2, Bs2, acc,
                SJob{nullptr, nullptr}, SJob{nullptr, nullptr}, SJob{nullptr, nullptr},
                t, wm, wn, l15, quad, l7);
  ktile2<SW, -1>(A0, Bs0, acc,
                 SJob{nullptr, nullptr}, SJob{nullptr, nullptr}, SJob{nullptr, nullptr},
                 t, wm, wn, l15, quad, l7);
}

// ------- out GEMM: A (8192x1024) bf16, Bt (1024x1024) -> fp32; grid (8,32) -------
__global__ __launch_bounds__(512, 2) void gemm_out8(const unsigned short* __restrict__ A,
                                                    const unsigned short* __restrict__ Bt,
                                                    const float* __restrict__ bias,
                                                    float* __restrict__ Cout) {
  extern __shared__ unsigned short lds[];
  unsigned short* Asl = lds;
  unsigned short* Bsl = lds + 3 * 16384;
  const int t = threadIdx.x;
  const int w = t >> 6, lane = t & 63;
  const int l15 = lane & 15, quad = lane >> 4, l7 = l15 & 7;
  const int bm = blockIdx.y * 256, bn = blockIdx.x * 128;
  const int wm = (w >> 1) * 64, wn = (w & 1) * 64;
  const unsigned short* Ag = A + (size_t)bm * 1024;
  const unsigned short* Bg = Bt + (size_t)bn * 1024;

  f32x4 acc[4][4] = {};
  gemm_core<false>(Ag, Bg, Asl, Bsl, acc, t, wm, wn, l15, quad, l7);

  #pragma unroll
  for (int ni = 0; ni < 4; ni++) {
    int col = bn + wn + ni * 16 + l15;
    float bvv = bias[col];
    #pragma unroll
    for (int mi = 0; mi < 4; mi++) {
      int row0 = bm + wm + mi * 16 + quad * 4;
      #pragma unroll
      for (int r = 0; r < 4; r++)
        Cout[(size_t)(row0 + r) * 1024 + col] = acc[mi][ni][r] + bvv;
    }
  }
}

// ------------------------- flash attention v3 (unchanged) -------------------------
#define PLD 72
#define VROWS 65   // per-buffer V rows: 64 V' + 1 mask row
__global__ __launch_bounds__(256) void attn_kernel(const unsigned short* __restrict__ Q,
                                                   const unsigned short* __restrict__ Kb,
                                                   const unsigned short* __restrict__ Vt,
                                                   const int* __restrict__ masks,
                                                   unsigned short* __restrict__ O) {
  __shared__ __align__(16) unsigned short Pl[128 * PLD];            // P tiles (stride 72)
  __shared__ __align__(16) unsigned short Ks[2 * 64 * 64];          // K dbuf
  __shared__ __align__(16) unsigned short Vs[(2 * VROWS + 15) * 64];// V' dbuf + mask rows
  const int t = threadIdx.x;
  const int wave = t >> 6, lane = t & 63;
  const int l15 = lane & 15, quad = lane >> 4;
  const int l7 = l15 & 7;
  const int bh = blockIdx.x;       // 0..127  (XCD-locality key)
  const int qt = blockIdx.y;       // 0..7
  const int b = bh >> 4, h = bh & 15;

  const unsigned short* Qg = Q + ((size_t)bh * S_ + qt * 128) * DK_;
  const unsigned short* Kg = Kb + (size_t)bh * S_ * DK_;
  const unsigned short* Vg = Vt + (size_t)bh * DV_ * S_;
  const int wslot = (t & ~63);

  int mv[4];
  #pragma unroll
  for (int j = 0; j < 4; j++)
    mv[j] = masks[b * S_ + (j * 4 + wave) * 64 + lane];

  // Q fragments (B-operand) straight from global (L2-resident)
  short8 aq[2][2];
  #pragma unroll
  for (int mb = 0; mb < 2; mb++)
    #pragma unroll
    for (int kf = 0; kf < 2; kf++)
      aq[mb][kf] = *(const short8*)(Qg + (size_t)(wave * 32 + mb * 16 + l15) * 64 + kf * 32 + quad * 8);

  auto stage = [&](int kt, int buf) {
    const unsigned short* Kt = Kg + (size_t)kt * 64 * DK_;
    unsigned short* Kd = &Ks[buf * 4096];
    unsigned short* Vd = &Vs[buf * (VROWS * 64)];
    #pragma unroll
    for (int i = 0; i < 2; i++) {
      int p = i * 256 + t;
      int rk = p >> 3, ck = (p & 7) ^ (rk & 7);
      ld_lds16(Kt + (size_t)rk * DK_ + ck * 8, &Kd[(i * 256 + wslot) * 8]);
      ld_lds16(Vg + (size_t)rk * S_ + kt * 64 + ck * 8, &Vd[(i * 256 + wslot) * 8]);
    }
    if (wave == (kt & 3))
      Vd[64 * 64 + lane] = (mv[kt >> 2] != 0) ? (unsigned short)0x3F80 : (unsigned short)0;
  };

  f32x4 o_acc[2][5] = {};   // [mb][n]; n==4 is the l column (col 0 valid)

  stage(0, 0);
  __syncthreads();          // tile 0 resident

  #pragma unroll 2
  for (int kt = 0; kt < 16; kt++) {
    const int cur = kt & 1;
    if (kt < 15) stage(kt + 1, cur ^ 1);   // in flight across the compute below
    const unsigned short* Kc = &Ks[cur * 4096];
    const unsigned short* Vc = &Vs[cur * (VROWS * 64)];

    // S^T = K·Q^T : lane l15 = q, quad*4+r = key (within 16-tile)
    f32x4 sc[2][4];
    #pragma unroll
    for (int n = 0; n < 4; n++) {
      short8 bk0 = *(const short8*)&Kc[(n * 16 + l15) * 64 + (quad ^ l7) * 8];
      short8 bk1 = *(const short8*)&Kc[(n * 16 + l15) * 64 + ((4 + quad) ^ l7) * 8];
      #pragma unroll
      for (int mb = 0; mb < 2; mb++) {
        f32x4 c = {};
        c = __builtin_amdgcn_mfma_f32_16x16x32_bf16(bk0, aq[mb][0], c, 0, 0, 0);
        c = __builtin_amdgcn_mfma_f32_16x16x32_bf16(bk1, aq[mb][1], c, 0, 0, 0);
        sc[mb][n] = c;
      }
    }
    // exp2 (raw v_exp_f32) + packed b64 P write: P[q][key]
    #pragma unroll
    for (int mb = 0; mb < 2; mb++)
      #pragma unroll
      for (int n = 0; n < 4; n++) {
        ushort4 pk;
        pk.x = f2bf_trunc(__builtin_amdgcn_exp2f(sc[mb][n][0]));
        pk.y = f2bf_trunc(__builtin_amdgcn_exp2f(sc[mb][n][1]));
        pk.z = f2bf_trunc(__builtin_amdgcn_exp2f(sc[mb][n][2]));
        pk.w = f2bf_trunc(__builtin_amdgcn_exp2f(sc[mb][n][3]));
        *(ushort4*)&Pl[(wave * 32 + mb * 16 + l15) * PLD + n * 16 + quad * 4] = pk;
      }
    // PV (+l): O[q][d] += P[q][key]·V'[key][d]; n=4 reads mask row -> l in col 0
    #pragma unroll
    for (int kf = 0; kf < 2; kf++) {
      short8 ap[2];
      #pragma unroll
      for (int mb = 0; mb < 2; mb++)
        ap[mb] = *(const short8*)&Pl[(wave * 32 + mb * 16 + l15) * PLD + kf * 32 + quad * 8];
      #pragma unroll
      for (int n = 0; n < 5; n++) {
        short8 bv = *(const short8*)&Vc[(n * 16 + l15) * 64 + ((kf * 4 + quad) ^ l7) * 8];
        #pragma unroll
        for (int mb = 0; mb < 2; mb++)
          o_acc[mb][n] = __builtin_amdgcn_mfma_f32_16x16x32_bf16(ap[mb], bv, o_acc[mb][n], 0, 0, 0);
      }
    }
    __syncthreads();   // drains this iter's stage loads (issued ~1000cy ago)
  }

  // epilogue: l lives in o_acc[mb][4][r] at l15==0 -> broadcast within quad
  #pragma unroll
  for (int mb = 0; mb < 2; mb++)
    #pragma unroll
    for (int r = 0; r < 4; r++) {
      float l = __shfl(o_acc[mb][4][r], lane & 48, 64);
      float inv = __builtin_amdgcn_rcpf(l);
      int qrow = qt * 128 + wave * 32 + mb * 16 + quad * 4 + r;
      #pragma unroll
      for (int n = 0; n < 4; n++) {
        int col = h * 64 + n * 16 + l15;
        O[((size_t)b * S_ + qrow) * D_ + col] = f2bf(o_acc[mb][n][r] * inv);
      }
    }
}

extern "C" void kernel_launch(void* const* d_in, const int* in_sizes, int n_in,
                              void* d_out, int out_size, void* d_ws, size_t ws_size,
                              hipStream_t stream) {
  (void)in_sizes; (void)n_in; (void)out_size; (void)ws_size;
  const float* x  = (const float*)d_in[0];
  const int* masks = (const int*)d_in[1];
  const float* Wq = (const float*)d_in[2];
  const float* bq = (const float*)d_in[3];
  const float* Wk = (const float*)d_in[4];
  const float* bk = (const float*)d_in[5];
  const float* Wv = (const float*)d_in[6];
  const float* bv = (const float*)d_in[7];
  const float* Wo = (const float*)d_in[8];
  const float* bo = (const float*)d_in[9];

  char* p = (char*)d_ws;
  unsigned short* xb    = (unsigned short*)p; p += (size_t)8192 * 1024 * 2;
  unsigned short* WqkvT = (unsigned short*)p; p += (size_t)3072 * 1024 * 2;
  unsigned short* WoT   = (unsigned short*)p; p += (size_t)1024 * 1024 * 2;
  unsigned short* q     = (unsigned short*)p; p += (size_t)8192 * 1024 * 2;
  unsigned short* kk    = (unsigned short*)p; p += (size_t)8192 * 1024 * 2;
  unsigned short* vT    = (unsigned short*)p; p += (size_t)8192 * 1024 * 2;
  unsigned short* at    = (unsigned short*)p; p += (size_t)8192 * 1024 * 2;

  static bool attr_done = false;
  if (!attr_done) {
    hipFuncSetAttribute((const void*)gemm_qkv8, hipFuncAttributeMaxDynamicSharedMemorySize, 131072);
    hipFuncSetAttribute((const void*)gemm_out8, hipFuncAttributeMaxDynamicSharedMemorySize, 147456);
    attr_done = true;
  }

  prep_kernel<<<dim3(16, 16, 36), 256, 0, stream>>>(
      x, xb, Wq, Wk, Wv, Wo,
      WqkvT, WqkvT + (size_t)1024 * 1024, WqkvT + (size_t)2048 * 1024, WoT);
  gemm_qkv8<<<dim3(12, 32), 512, 131072, stream>>>(xb, WqkvT, bq, bk, bv, masks, q, kk, vT);
  attn_kernel<<<dim3(128, 8), 256, 0, stream>>>(q, kk, vT, masks, at);
  gemm_out8<<<dim3(8, 32), 512, 147456, stream>>>(at, WoT, bo, (float*)d_out);
}

// Round 7
// 241.845 us; speedup vs baseline: 1.0461x; 1.0461x over previous
//
#include <hip/hip_runtime.h>
#include <stdint.h>

#define B_ 8
#define S_ 1024
#define D_ 1024
#define H_ 16
#define DK_ 64
#define DV_ 64

typedef __attribute__((ext_vector_type(8))) short short8;
typedef __attribute__((ext_vector_type(4))) float f32x4;

__device__ __forceinline__ unsigned short f2bf(float f) {
  union { float f; unsigned u; } v; v.f = f;
  return (unsigned short)((v.u + 0x7fffu + ((v.u >> 16) & 1u)) >> 16);
}
__device__ __forceinline__ unsigned short f2bf_trunc(float f) {
  union { float f; unsigned u; } v; v.f = f;
  return (unsigned short)(v.u >> 16);
}

// async global->LDS, 16B per lane; LDS dest = wave-uniform base + lane*16
__device__ __forceinline__ void ld_lds16(const unsigned short* g, unsigned short* l) {
  __builtin_amdgcn_global_load_lds((const __attribute__((address_space(1))) void*)g,
                                   (__attribute__((address_space(3))) void*)l, 16, 0, 0);
}

// -------- fused prep: x fp32->bf16 (z>=4) + 4 weight transposes (z<4) --------
__global__ __launch_bounds__(256) void prep_kernel(const float* __restrict__ x,
                                                   unsigned short* __restrict__ xb,
                                                   const float* __restrict__ W0,
                                                   const float* __restrict__ W1,
                                                   const float* __restrict__ W2,
                                                   const float* __restrict__ W3,
                                                   unsigned short* __restrict__ T0,
                                                   unsigned short* __restrict__ T1,
                                                   unsigned short* __restrict__ T2,
                                                   unsigned short* __restrict__ T3) {
  const int z = blockIdx.z;
  if (z >= 4) {
    size_t blk = (size_t)(z - 4) * 256 + blockIdx.y * 16 + blockIdx.x;
    size_t i = (blk * 256 + threadIdx.x) * 4;
    float4 v = *(const float4*)(x + i);
    ushort4 o;
    o.x = f2bf(v.x); o.y = f2bf(v.y); o.z = f2bf(v.z); o.w = f2bf(v.w);
    *(ushort4*)(xb + i) = o;
    return;
  }
  __shared__ __align__(16) unsigned short tl[64][65];
  const float* W; unsigned short* Wt;
  switch (z) {
    case 0: W = W0; Wt = T0; break;
    case 1: W = W1; Wt = T1; break;
    case 2: W = W2; Wt = T2; break;
    default: W = W3; Wt = T3; break;
  }
  const int xx = threadIdx.x & 63;
  const int y4 = threadIdx.x >> 6;
  const int bn = blockIdx.x * 64;   // N base
  const int bk = blockIdx.y * 64;   // K base
  #pragma unroll
  for (int r = y4; r < 64; r += 4)
    tl[r][xx] = f2bf(W[(size_t)(bk + r) * 1024 + bn + xx]);
  __syncthreads();
  #pragma unroll
  for (int r = y4; r < 64; r += 4)
    Wt[(size_t)(bn + r) * 1024 + bk + xx] = tl[xx][r];
}

// ============ 128x128-tile GEMM, 256 thr (4 waves 2x2), 64 KiB LDS ============
// 2 blocks/CU: same 2 waves/SIMD as the 512-thr variants, but TWO independent
// barrier domains per CU -- one block's waves issue while the other drains.
// Per K-tile: r3's proven counted-vmcnt 4-phase schedule (B-frags held in regs
// from p0/p1; A(J+1) staged at p0; B(J+2) staged at p2 -- after p1's lgkmcnt(0)
// certified all reads of B slot J%2; vmcnt(4) once per tile, 0 only at tail).

struct SJob { const unsigned short* g; unsigned short* l; };

// stage 128 rows x 64 cols (bf16) from G (row stride 1024) into 16 KB LDS tile,
// 256 threads; linear dest, pre-swizzled source column blocks (cb ^ (r&7)).
__device__ __forceinline__ void stage_t256(const unsigned short* __restrict__ G,
                                           unsigned short* __restrict__ L, int t) {
  #pragma unroll
  for (int i = 0; i < 4; i++) {
    int s = i * 256 + t;
    int r = s >> 3, cb = s & 7;
    int c = cb ^ (r & 7);
    ld_lds16(G + (size_t)r * 1024 + c * 8, L + (size_t)s * 8);
  }
}

template <bool SW>
__device__ __forceinline__ f32x4 MM(short8 a, short8 b, f32x4 c) {
  if constexpr (SW) return __builtin_amdgcn_mfma_f32_16x16x32_bf16(b, a, c, 0, 0, 0);
  else              return __builtin_amdgcn_mfma_f32_16x16x32_bf16(a, b, c, 0, 0, 0);
}

// one K-tile: 4 phases x 8 MFMA. VM: vmcnt at tile end (4 steady, 0 drain, -1 none).
template <bool SW, int VM>
__device__ __forceinline__ void ktile128(const unsigned short* __restrict__ As_,
                                         const unsigned short* __restrict__ Bs_,
                                         f32x4 (&acc)[4][4],
                                         SJob sA, SJob sB,
                                         int t, int wm, int wn, int l15, int quad, int l7) {
  const int cb0 = (quad ^ l7) * 8;         // kf0 col block (swizzled)
  const int cb1 = ((4 | quad) ^ l7) * 8;   // kf1 col block
  short8 b0[4], b1[4], a0, a1;

  // ---------- phase 0: B kf0 (held) + A mi{0,1} kf0; stage A(J+1) ----------
  #pragma unroll
  for (int ni = 0; ni < 4; ni++)
    b0[ni] = *(const short8*)&Bs_[(wn + ni * 16 + l15) * 64 + cb0];
  a0 = *(const short8*)&As_[(wm + 0 * 16 + l15) * 64 + cb0];
  a1 = *(const short8*)&As_[(wm + 1 * 16 + l15) * 64 + cb0];
  if (sA.g) stage_t256(sA.g, sA.l, t);
  __builtin_amdgcn_s_barrier();
  asm volatile("s_waitcnt lgkmcnt(0)" ::: "memory");
  __builtin_amdgcn_s_setprio(1);
  #pragma unroll
  for (int ni = 0; ni < 4; ni++) {
    acc[0][ni] = MM<SW>(a0, b0[ni], acc[0][ni]);
    acc[1][ni] = MM<SW>(a1, b0[ni], acc[1][ni]);
  }
  __builtin_amdgcn_s_setprio(0);
  __builtin_amdgcn_s_barrier();

  // ---------- phase 1: B kf1 (held) + A mi{0,1} kf1 ----------
  #pragma unroll
  for (int ni = 0; ni < 4; ni++)
    b1[ni] = *(const short8*)&Bs_[(wn + ni * 16 + l15) * 64 + cb1];
  a0 = *(const short8*)&As_[(wm + 0 * 16 + l15) * 64 + cb1];
  a1 = *(const short8*)&As_[(wm + 1 * 16 + l15) * 64 + cb1];
  __builtin_amdgcn_s_barrier();
  asm volatile("s_waitcnt lgkmcnt(0)" ::: "memory");
  __builtin_amdgcn_s_setprio(1);
  #pragma unroll
  for (int ni = 0; ni < 4; ni++) {
    acc[0][ni] = MM<SW>(a0, b1[ni], acc[0][ni]);
    acc[1][ni] = MM<SW>(a1, b1[ni], acc[1][ni]);
  }
  __builtin_amdgcn_s_setprio(0);
  __builtin_amdgcn_s_barrier();

  // ---------- phase 2: A mi{2,3} kf0; stage B(J+2) (B-slot reads drained @p1) ----------
  a0 = *(const short8*)&As_[(wm + 2 * 16 + l15) * 64 + cb0];
  a1 = *(const short8*)&As_[(wm + 3 * 16 + l15) * 64 + cb0];
  if (sB.g) stage_t256(sB.g, sB.l, t);
  __builtin_amdgcn_s_barrier();
  asm volatile("s_waitcnt lgkmcnt(0)" ::: "memory");
  __builtin_amdgcn_s_setprio(1);
  #pragma unroll
  for (int ni = 0; ni < 4; ni++) {
    acc[2][ni] = MM<SW>(a0, b0[ni], acc[2][ni]);
    acc[3][ni] = MM<SW>(a1, b0[ni], acc[3][ni]);
  }
  __builtin_amdgcn_s_setprio(0);
  __builtin_amdgcn_s_barrier();

  // ---------- phase 3: A mi{2,3} kf1; vmcnt ----------
  a0 = *(const short8*)&As_[(wm + 2 * 16 + l15) * 64 + cb1];
  a1 = *(const short8*)&As_[(wm + 3 * 16 + l15) * 64 + cb1];
  __builtin_amdgcn_s_barrier();
  asm volatile("s_waitcnt lgkmcnt(0)" ::: "memory");
  __builtin_amdgcn_s_setprio(1);
  #pragma unroll
  for (int ni = 0; ni < 4; ni++) {
    acc[2][ni] = MM<SW>(a0, b1[ni], acc[2][ni]);
    acc[3][ni] = MM<SW>(a1, b1[ni], acc[3][ni]);
  }
  __builtin_amdgcn_s_setprio(0);
  if constexpr (VM == 4) asm volatile("s_waitcnt vmcnt(4)" ::: "memory");
  if constexpr (VM == 0) asm volatile("s_waitcnt vmcnt(0)" ::: "memory");
  __builtin_amdgcn_s_barrier();
}

// full 128x128 gemm core: 16 K-tiles, A/B double-buffered (16 KB slots)
template <bool SW>
__device__ __forceinline__ void gemm_core128(const unsigned short* __restrict__ Ag,
                                             const unsigned short* __restrict__ Bg,
                                             unsigned short* __restrict__ Asl,
                                             unsigned short* __restrict__ Bsl,
                                             f32x4 (&acc)[4][4],
                                             int t, int wm, int wn, int l15, int quad, int l7) {
  unsigned short* A0 = Asl;
  unsigned short* A1 = Asl + 8192;
  unsigned short* B0 = Bsl;
  unsigned short* B1 = Bsl + 8192;

  // prologue: A(0)->A0, B(0)->B0, B(1)->B1 (12 loads/thread);
  // vmcnt(4): A0,B0 landed; B1's 4 in flight.
  stage_t256(Ag,      A0, t);
  stage_t256(Bg,      B0, t);
  stage_t256(Bg + 64, B1, t);
  asm volatile("s_waitcnt vmcnt(4)" ::: "memory");
  __builtin_amdgcn_s_barrier();

  // steady state: tile J stages A(J+1)->slot (J+1)%2 at p0, B(J+2)->slot J%2 at p2;
  // vmcnt(4) at tile end certifies A(J+1)+B(J+1), leaves B(J+2) in flight.
  #pragma unroll 1
  for (int J = 0; J < 14; J += 2) {
    ktile128<SW, 4>(A0, B0, acc,
                    SJob{Ag + (size_t)(J + 1) * 64, A1},
                    SJob{Bg + (size_t)(J + 2) * 64, B0},
                    t, wm, wn, l15, quad, l7);
    ktile128<SW, 4>(A1, B1, acc,
                    SJob{Ag + (size_t)(J + 2) * 64, A0},
                    SJob{Bg + (size_t)(J + 3) * 64, B1},
                    t, wm, wn, l15, quad, l7);
  }
  // tile 14: stage A(15) only; full drain. tile 15: nothing in flight.
  ktile128<SW, 0>(A0, B0, acc,
                  SJob{Ag + (size_t)15 * 64, A1}, SJob{nullptr, nullptr},
                  t, wm, wn, l15, quad, l7);
  ktile128<SW, -1>(A1, B1, acc,
                   SJob{nullptr, nullptr}, SJob{nullptr, nullptr},
                   t, wm, wn, l15, quad, l7);
}

// ------------- fused QKV GEMM: A (8192x1024), Bt (3072x1024) -------------
// grid (24,64), 256 thr, 64 KiB LDS -> 2 blocks/CU, 3 perfectly-packed rounds.
// blockIdx.x 0..7 -> q (scaled), 8..15 -> k, 16..23 -> v (transposed, mask folded)
__global__ __launch_bounds__(256, 2) void gemm_qkv8(const unsigned short* __restrict__ A,
                                                    const unsigned short* __restrict__ Bt,
                                                    const float* __restrict__ bq,
                                                    const float* __restrict__ bk,
                                                    const float* __restrict__ bv,
                                                    const int* __restrict__ masks,
                                                    unsigned short* __restrict__ q,
                                                    unsigned short* __restrict__ kk,
                                                    unsigned short* __restrict__ vT) {
  extern __shared__ unsigned short lds[];
  unsigned short* Asl = lds;            // 2 x 128x64
  unsigned short* Bsl = lds + 16384;    // 2 x 128x64
  const int t = threadIdx.x;
  const int wave = t >> 6, lane = t & 63;
  const int l15 = lane & 15, quad = lane >> 4, l7 = l15 & 7;
  const int bm = blockIdx.y * 128, bn = blockIdx.x * 128;
  const int wm = (wave & 1) * 64, wn = (wave >> 1) * 64;
  const bool vsec = (blockIdx.x >= 16);
  const unsigned short* Ag = A + (size_t)bm * 1024;
  const unsigned short* Bg = Bt + (size_t)bn * 1024;

  f32x4 acc[4][4] = {};
  if (!vsec) gemm_core128<false>(Ag, Bg, Asl, Bsl, acc, t, wm, wn, l15, quad, l7);
  else       gemm_core128<true >(Ag, Bg, Asl, Bsl, acc, t, wm, wn, l15, quad, l7);

  if (!vsec) {
    int sec = blockIdx.x >> 3;   // 0 -> q, 1 -> k
    const float* bsel = (sec == 0) ? bq : bk;
    unsigned short* dst = (sec == 0) ? q : kk;
    float scale = (sec == 0) ? 0.180336880f : 1.0f;  // 0.125*log2(e) folded into q
    #pragma unroll
    for (int ni = 0; ni < 4; ni++) {
      int c = (bn & 1023) + wn + ni * 16 + l15;
      float bvv = bsel[c];
      int hh = c >> 6, d = c & 63;
      #pragma unroll
      for (int mi = 0; mi < 4; mi++) {
        int row0 = bm + wm + mi * 16 + quad * 4;
        #pragma unroll
        for (int r = 0; r < 4; r++) {
          int row = row0 + r;
          int b = row >> 10, s = row & 1023;
          dst[(((size_t)(b * H_ + hh)) * S_ + s) * DK_ + d] = f2bf((acc[mi][ni][r] + bvv) * scale);
        }
      }
    }
  } else {
    // transposed accum: lane l15 -> row (s), quad*4+r -> col (d); mask folded
    #pragma unroll
    for (int ni = 0; ni < 4; ni++) {
      int cbase = (bn & 1023) + wn + ni * 16;
      #pragma unroll
      for (int mi = 0; mi < 4; mi++) {
        int row = bm + wm + mi * 16 + l15;
        int b = row >> 10, s = row & 1023;
        float mf = (masks[b * S_ + s] != 0) ? 1.0f : 0.0f;
        #pragma unroll
        for (int r = 0; r < 4; r++) {
          int c = cbase + quad * 4 + r;
          int hh = c >> 6, d = c & 63;
          vT[(((size_t)(b * H_ + hh)) * DV_ + d) * S_ + s] = f2bf((acc[mi][ni][r] + bv[c]) * mf);
        }
      }
    }
  }
}

// ------- out GEMM: A (8192x1024) bf16, Bt (1024x1024) -> fp32; grid (8,64) -------
// 512 blocks at 2/CU = exactly 1 round.
__global__ __launch_bounds__(256, 2) void gemm_out8(const unsigned short* __restrict__ A,
                                                    const unsigned short* __restrict__ Bt,
                                                    const float* __restrict__ bias,
                                                    float* __restrict__ Cout) {
  extern __shared__ unsigned short lds[];
  unsigned short* Asl = lds;
  unsigned short* Bsl = lds + 16384;
  const int t = threadIdx.x;
  const int wave = t >> 6, lane = t & 63;
  const int l15 = lane & 15, quad = lane >> 4, l7 = l15 & 7;
  const int bm = blockIdx.y * 128, bn = blockIdx.x * 128;
  const int wm = (wave & 1) * 64, wn = (wave >> 1) * 64;
  const unsigned short* Ag = A + (size_t)bm * 1024;
  const unsigned short* Bg = Bt + (size_t)bn * 1024;

  f32x4 acc[4][4] = {};
  gemm_core128<false>(Ag, Bg, Asl, Bsl, acc, t, wm, wn, l15, quad, l7);

  #pragma unroll
  for (int ni = 0; ni < 4; ni++) {
    int col = bn + wn + ni * 16 + l15;
    float bvv = bias[col];
    #pragma unroll
    for (int mi = 0; mi < 4; mi++) {
      int row0 = bm + wm + mi * 16 + quad * 4;
      #pragma unroll
      for (int r = 0; r < 4; r++)
        Cout[(size_t)(row0 + r) * 1024 + col] = acc[mi][ni][r] + bvv;
    }
  }
}

// ------------------------- flash attention v3 (unchanged) -------------------------
#define PLD 72
#define VROWS 65   // per-buffer V rows: 64 V' + 1 mask row
__global__ __launch_bounds__(256) void attn_kernel(const unsigned short* __restrict__ Q,
                                                   const unsigned short* __restrict__ Kb,
                                                   const unsigned short* __restrict__ Vt,
                                                   const int* __restrict__ masks,
                                                   unsigned short* __restrict__ O) {
  __shared__ __align__(16) unsigned short Pl[128 * PLD];            // P tiles (stride 72)
  __shared__ __align__(16) unsigned short Ks[2 * 64 * 64];          // K dbuf
  __shared__ __align__(16) unsigned short Vs[(2 * VROWS + 15) * 64];// V' dbuf + mask rows
  const int t = threadIdx.x;
  const int wave = t >> 6, lane = t & 63;
  const int l15 = lane & 15, quad = lane >> 4;
  const int l7 = l15 & 7;
  const int bh = blockIdx.x;       // 0..127  (XCD-locality key)
  const int qt = blockIdx.y;       // 0..7
  const int b = bh >> 4, h = bh & 15;

  const unsigned short* Qg = Q + ((size_t)bh * S_ + qt * 128) * DK_;
  const unsigned short* Kg = Kb + (size_t)bh * S_ * DK_;
  const unsigned short* Vg = Vt + (size_t)bh * DV_ * S_;
  const int wslot = (t & ~63);

  int mv[4];
  #pragma unroll
  for (int j = 0; j < 4; j++)
    mv[j] = masks[b * S_ + (j * 4 + wave) * 64 + lane];

  // Q fragments (B-operand) straight from global (L2-resident)
  short8 aq[2][2];
  #pragma unroll
  for (int mb = 0; mb < 2; mb++)
    #pragma unroll
    for (int kf = 0; kf < 2; kf++)
      aq[mb][kf] = *(const short8*)(Qg + (size_t)(wave * 32 + mb * 16 + l15) * 64 + kf * 32 + quad * 8);

  auto stage = [&](int kt, int buf) {
    const unsigned short* Kt = Kg + (size_t)kt * 64 * DK_;
    unsigned short* Kd = &Ks[buf * 4096];
    unsigned short* Vd = &Vs[buf * (VROWS * 64)];
    #pragma unroll
    for (int i = 0; i < 2; i++) {
      int p = i * 256 + t;
      int rk = p >> 3, ck = (p & 7) ^ (rk & 7);
      ld_lds16(Kt + (size_t)rk * DK_ + ck * 8, &Kd[(i * 256 + wslot) * 8]);
      ld_lds16(Vg + (size_t)rk * S_ + kt * 64 + ck * 8, &Vd[(i * 256 + wslot) * 8]);
    }
    if (wave == (kt & 3))
      Vd[64 * 64 + lane] = (mv[kt >> 2] != 0) ? (unsigned short)0x3F80 : (unsigned short)0;
  };

  f32x4 o_acc[2][5] = {};   // [mb][n]; n==4 is the l column (col 0 valid)

  stage(0, 0);
  __syncthreads();          // tile 0 resident

  #pragma unroll 2
  for (int kt = 0; kt < 16; kt++) {
    const int cur = kt & 1;
    if (kt < 15) stage(kt + 1, cur ^ 1);   // in flight across the compute below
    const unsigned short* Kc = &Ks[cur * 4096];
    const unsigned short* Vc = &Vs[cur * (VROWS * 64)];

    // S^T = K·Q^T : lane l15 = q, quad*4+r = key (within 16-tile)
    f32x4 sc[2][4];
    #pragma unroll
    for (int n = 0; n < 4; n++) {
      short8 bk0 = *(const short8*)&Kc[(n * 16 + l15) * 64 + (quad ^ l7) * 8];
      short8 bk1 = *(const short8*)&Kc[(n * 16 + l15) * 64 + ((4 + quad) ^ l7) * 8];
      #pragma unroll
      for (int mb = 0; mb < 2; mb++) {
        f32x4 c = {};
        c = __builtin_amdgcn_mfma_f32_16x16x32_bf16(bk0, aq[mb][0], c, 0, 0, 0);
        c = __builtin_amdgcn_mfma_f32_16x16x32_bf16(bk1, aq[mb][1], c, 0, 0, 0);
        sc[mb][n] = c;
      }
    }
    // exp2 (raw v_exp_f32) + packed b64 P write: P[q][key]
    #pragma unroll
    for (int mb = 0; mb < 2; mb++)
      #pragma unroll
      for (int n = 0; n < 4; n++) {
        ushort4 pk;
        pk.x = f2bf_trunc(__builtin_amdgcn_exp2f(sc[mb][n][0]));
        pk.y = f2bf_trunc(__builtin_amdgcn_exp2f(sc[mb][n][1]));
        pk.z = f2bf_trunc(__builtin_amdgcn_exp2f(sc[mb][n][2]));
        pk.w = f2bf_trunc(__builtin_amdgcn_exp2f(sc[mb][n][3]));
        *(ushort4*)&Pl[(wave * 32 + mb * 16 + l15) * PLD + n * 16 + quad * 4] = pk;
      }
    // PV (+l): O[q][d] += P[q][key]·V'[key][d]; n=4 reads mask row -> l in col 0
    #pragma unroll
    for (int kf = 0; kf < 2; kf++) {
      short8 ap[2];
      #pragma unroll
      for (int mb = 0; mb < 2; mb++)
        ap[mb] = *(const short8*)&Pl[(wave * 32 + mb * 16 + l15) * PLD + kf * 32 + quad * 8];
      #pragma unroll
      for (int n = 0; n < 5; n++) {
        short8 bv = *(const short8*)&Vc[(n * 16 + l15) * 64 + ((kf * 4 + quad) ^ l7) * 8];
        #pragma unroll
        for (int mb = 0; mb < 2; mb++)
          o_acc[mb][n] = __builtin_amdgcn_mfma_f32_16x16x32_bf16(ap[mb], bv, o_acc[mb][n], 0, 0, 0);
      }
    }
    __syncthreads();   // drains this iter's stage loads (issued ~1000cy ago)
  }

  // epilogue: l lives in o_acc[mb][4][r] at l15==0 -> broadcast within quad
  #pragma unroll
  for (int mb = 0; mb < 2; mb++)
    #pragma unroll
    for (int r = 0; r < 4; r++) {
      float l = __shfl(o_acc[mb][4][r], lane & 48, 64);
      float inv = __builtin_amdgcn_rcpf(l);
      int qrow = qt * 128 + wave * 32 + mb * 16 + quad * 4 + r;
      #pragma unroll
      for (int n = 0; n < 4; n++) {
        int col = h * 64 + n * 16 + l15;
        O[((size_t)b * S_ + qrow) * D_ + col] = f2bf(o_acc[mb][n][r] * inv);
      }
    }
}

extern "C" void kernel_launch(void* const* d_in, const int* in_sizes, int n_in,
                              void* d_out, int out_size, void* d_ws, size_t ws_size,
                              hipStream_t stream) {
  (void)in_sizes; (void)n_in; (void)out_size; (void)ws_size;
  const float* x  = (const float*)d_in[0];
  const int* masks = (const int*)d_in[1];
  const float* Wq = (const float*)d_in[2];
  const float* bq = (const float*)d_in[3];
  const float* Wk = (const float*)d_in[4];
  const float* bk = (const float*)d_in[5];
  const float* Wv = (const float*)d_in[6];
  const float* bv = (const float*)d_in[7];
  const float* Wo = (const float*)d_in[8];
  const float* bo = (const float*)d_in[9];

  char* p = (char*)d_ws;
  unsigned short* xb    = (unsigned short*)p; p += (size_t)8192 * 1024 * 2;
  unsigned short* WqkvT = (unsigned short*)p; p += (size_t)3072 * 1024 * 2;
  unsigned short* WoT   = (unsigned short*)p; p += (size_t)1024 * 1024 * 2;
  unsigned short* q     = (unsigned short*)p; p += (size_t)8192 * 1024 * 2;
  unsigned short* kk    = (unsigned short*)p; p += (size_t)8192 * 1024 * 2;
  unsigned short* vT    = (unsigned short*)p; p += (size_t)8192 * 1024 * 2;
  unsigned short* at    = (unsigned short*)p; p += (size_t)8192 * 1024 * 2;

  static bool attr_done = false;
  if (!attr_done) {
    hipFuncSetAttribute((const void*)gemm_qkv8, hipFuncAttributeMaxDynamicSharedMemorySize, 65536);
    hipFuncSetAttribute((const void*)gemm_out8, hipFuncAttributeMaxDynamicSharedMemorySize, 65536);
    attr_done = true;
  }

  prep_kernel<<<dim3(16, 16, 36), 256, 0, stream>>>(
      x, xb, Wq, Wk, Wv, Wo,
      WqkvT, WqkvT + (size_t)1024 * 1024, WqkvT + (size_t)2048 * 1024, WoT);
  gemm_qkv8<<<dim3(24, 64), 256, 65536, stream>>>(xb, WqkvT, bq, bk, bv, masks, q, kk, vT);
  attn_kernel<<<dim3(128, 8), 256, 0, stream>>>(q, kk, vT, masks, at);
  gemm_out8<<<dim3(8, 64), 256, 65536, stream>>>(at, WoT, bo, (float*)d_out);
}